// Round 9
// baseline (220.447 us; speedup 1.0000x reference)
//
#include <hip/hip_runtime.h>
#include <hip/hip_bf16.h>
#include <stdint.h>

typedef unsigned short u16;
typedef u16   us8    __attribute__((ext_vector_type(8)));
typedef __bf16 bf16x8 __attribute__((ext_vector_type(8)));
typedef float f32x4  __attribute__((ext_vector_type(4)));

#define DEV static __device__ __forceinline__

DEV u16 f2bf(float f) {                       // fp32 -> bf16 RNE
  uint32_t u = __builtin_bit_cast(uint32_t, f);
  u += 0x7FFFu + ((u >> 16) & 1u);
  return (u16)(u >> 16);
}
DEV float bf2f(u16 s) { return __builtin_bit_cast(float, (uint32_t)s << 16); }

DEV void gl16(const void* g, void* l) {       // async global->LDS, 16B/lane
  __builtin_amdgcn_global_load_lds((const __attribute__((address_space(1))) void*)g,
                                   (__attribute__((address_space(3))) void*)l, 16, 0, 0);
}

// ------- fused fp32 -> bf16 convert for x, Wq, Wk, Wv + bias concat -------
__global__ __launch_bounds__(256) void k_cvt_all(
    const float* __restrict__ x, const float* __restrict__ wq,
    const float* __restrict__ wk, const float* __restrict__ wv,
    const float* __restrict__ bq, const float* __restrict__ bk,
    u16* __restrict__ out, float* __restrict__ bQK, int xn4, int wn4) {
  int i = blockIdx.x * 256 + threadIdx.x;
  const int cvt_tot = xn4 + 3 * wn4;
  if (i < cvt_tot) {
    const float* src;
    int idx;
    if (i < xn4) { src = x; idx = i; }
    else {
      int j = i - xn4;
      if (j < wn4) { src = wq; idx = j; }
      else if (j < 2 * wn4) { src = wk; idx = j - wn4; }
      else { src = wv; idx = j - 2 * wn4; }
    }
    float4 v = reinterpret_cast<const float4*>(src)[idx];
    uint2 o;
    o.x = (uint32_t)f2bf(v.x) | ((uint32_t)f2bf(v.y) << 16);
    o.y = (uint32_t)f2bf(v.z) | ((uint32_t)f2bf(v.w) << 16);
    reinterpret_cast<uint2*>(out)[i] = o;
  } else {
    int j = i - cvt_tot;                 // bias copy: bq(256 f4) bk(256 f4)
    if (j < 256)      reinterpret_cast<float4*>(bQK)[j] = reinterpret_cast<const float4*>(bq)[j];
    else if (j < 512) reinterpret_cast<float4*>(bQK)[j] = reinterpret_cast<const float4*>(bk)[j - 256];
  }
}

// =================== 256x256-tile 2-phase NT GEMM body (R7) ===========
// 2 phases/K-tile split by A-half, B-frags held in regs, stage PH0->A1B1(t+1),
// PH1->A0B0(t+2), boundary vmcnt(4), counted-lgkm clusters, k-major MFMA,
// XOR swizzle + inverse-swizzled gl16 source.
#define SB0 __builtin_amdgcn_sched_barrier(0)
#define LGKM(N) do { asm volatile("s_waitcnt lgkmcnt(" #N ")" ::: "memory"); \
                     __builtin_amdgcn_sched_barrier(0); } while (0)

template <bool OUT_BF16, int BIAS_MODE>
DEV void gemm_body(const u16* __restrict__ A, const u16* __restrict__ B,
                   void* __restrict__ Cv, const float* __restrict__ bias,
                   int K, int lda, int ldb, int ldc, float alpha,
                   int m0, int n0, long long cbase, u16* AsB, u16* BsB) {
  const int t = threadIdx.x;
  const int lane = t & 63;
  const int wid = t >> 6;
  const int wm = wid >> 2;       // 0..1
  const int wn = wid & 3;        // 0..3
  const int l15 = lane & 15, l4 = lane >> 4;

  const int prow = t >> 3;
  const int scol = ((t & 7) ^ (prow & 7)) * 8;
  const u16* Abase = A + (long long)(m0 + prow) * lda + scol;
  const u16* Bbase = B + (long long)(n0 + prow) * ldb + scol;
  const long long a64 = (long long)64 * lda, a128 = (long long)128 * lda;
  const long long b64 = (long long)64 * ldb, b128 = (long long)128 * ldb;
  u16* AsT = AsB + t * 8;
  u16* BsT = BsB + t * 8;

#define STG_A(h, kt) { const u16* s_ = Abase + (h) * a128 + (long long)(kt) * 64; \
    u16* d_ = AsT + (((kt) & 1) * 2 + (h)) * 8192; gl16(s_, d_); gl16(s_ + a64, d_ + 4096); }
#define STG_B(h, kt) { const u16* s_ = Bbase + (h) * b128 + (long long)(kt) * 64; \
    u16* d_ = BsT + (((kt) & 1) * 2 + (h)) * 8192; gl16(s_, d_); gl16(s_ + b64, d_ + 4096); }

  const int aro = wm * 64 + l15;
  const int bro = wn * 32 + l15;
  const int cs0 = ((l4) ^ (l15 & 7)) * 8;
  const int cs1 = ((4 + l4) ^ (l15 & 7)) * 8;
#define LD(base, row, cs) (*(const bf16x8*)&(base)[(row) * 64 + (cs)])

  f32x4 acc[8][4];
#pragma unroll
  for (int i = 0; i < 8; ++i)
#pragma unroll
    for (int j = 0; j < 4; ++j) { f32x4 z = {0.f, 0.f, 0.f, 0.f}; acc[i][j] = z; }

  const int NT = K >> 6;

  STG_A(0, 0); STG_A(1, 0); STG_B(0, 0); STG_B(1, 0);
  STG_A(0, 1); STG_B(0, 1);
  asm volatile("s_waitcnt vmcnt(4)" ::: "memory");
  __builtin_amdgcn_s_barrier();

#define MK(f_, fn_, k_)                                                         \
  acc[f_][fn_] = __builtin_amdgcn_mfma_f32_16x16x32_bf16(af[f_][k_], bfr[fn_][k_], acc[f_][fn_], 0, 0, 0)
#define M1P(fn_, k_)                                                            \
  acc[4][fn_] = __builtin_amdgcn_mfma_f32_16x16x32_bf16(a1[k_], bfr[fn_][k_], acc[4][fn_], 0, 0, 0)
#define M1(f_, fn_, k_)                                                         \
  acc[4 + (f_)][fn_] = __builtin_amdgcn_mfma_f32_16x16x32_bf16(af1[(f_) - 1][k_], bfr[fn_][k_], acc[4 + (f_)][fn_], 0, 0, 0)

  for (int tt = 0; tt < NT; ++tt) {
    const int p = tt & 1;
    const bool s1 = (tt + 1 < NT);
    const bool s2 = (tt + 2 < NT);
    bf16x8 bfr[4][2];
    bf16x8 a1[2];

    // ---------------- PH0: qm = 0 ----------------
    {
      const u16* Ah  = AsB + (p * 2) * 8192;
      const u16* Ah1 = AsB + (p * 2 + 1) * 8192;
      const u16* Bh0 = BsB + (p * 2) * 8192;
      const u16* Bh1 = BsB + (p * 2 + 1) * 8192;
      bf16x8 af[4][2];
      bfr[0][0] = LD(Bh0, bro, cs0);      bfr[0][1] = LD(Bh0, bro, cs1);
      bfr[1][0] = LD(Bh0, bro + 16, cs0); bfr[1][1] = LD(Bh0, bro + 16, cs1);
      af[0][0]  = LD(Ah, aro, cs0);       af[0][1]  = LD(Ah, aro, cs1);
      SB0;
      bfr[2][0] = LD(Bh1, bro, cs0);      bfr[2][1] = LD(Bh1, bro, cs1);
      bfr[3][0] = LD(Bh1, bro + 16, cs0); bfr[3][1] = LD(Bh1, bro + 16, cs1);
      af[1][0]  = LD(Ah, aro + 16, cs0);  af[1][1]  = LD(Ah, aro + 16, cs1);
      SB0;
      af[2][0] = LD(Ah, aro + 32, cs0);   af[2][1] = LD(Ah, aro + 32, cs1);
      SB0;
      af[3][0] = LD(Ah, aro + 48, cs0);   af[3][1] = LD(Ah, aro + 48, cs1);
      if (s1) { STG_A(1, tt + 1); STG_B(1, tt + 1); }
      SB0;
      a1[0] = LD(Ah1, aro, cs0);          a1[1] = LD(Ah1, aro, cs1);
      SB0;
      LGKM(12);
      __builtin_amdgcn_s_setprio(1);
      MK(0, 0, 0); MK(0, 1, 0);
      LGKM(6);
      MK(0, 2, 0); MK(0, 3, 0);
      MK(1, 0, 0); MK(1, 1, 0); MK(1, 2, 0); MK(1, 3, 0);
      LGKM(4);
      MK(2, 0, 0); MK(2, 1, 0); MK(2, 2, 0); MK(2, 3, 0);
      LGKM(2);
      MK(3, 0, 0); MK(3, 1, 0); MK(3, 2, 0); MK(3, 3, 0);
      MK(0, 0, 1); MK(0, 1, 1); MK(0, 2, 1); MK(0, 3, 1);
      MK(1, 0, 1); MK(1, 1, 1); MK(1, 2, 1); MK(1, 3, 1);
      MK(2, 0, 1); MK(2, 1, 1); MK(2, 2, 1); MK(2, 3, 1);
      MK(3, 0, 1); MK(3, 1, 1); MK(3, 2, 1); MK(3, 3, 1);
      __builtin_amdgcn_s_setprio(0);
      __builtin_amdgcn_s_barrier();
    }

    // ---------------- PH1: qm = 1 (bfr + a1 held in registers) ----------------
    {
      const u16* Ah1 = AsB + (p * 2 + 1) * 8192;
      bf16x8 af1[3][2];
      af1[0][0] = LD(Ah1, aro + 16, cs0); af1[0][1] = LD(Ah1, aro + 16, cs1);
      SB0;
      af1[1][0] = LD(Ah1, aro + 32, cs0); af1[1][1] = LD(Ah1, aro + 32, cs1);
      SB0;
      af1[2][0] = LD(Ah1, aro + 48, cs0); af1[2][1] = LD(Ah1, aro + 48, cs1);
      if (s2) { STG_A(0, tt + 2); STG_B(0, tt + 2); }
      SB0;
      LGKM(6);
      __builtin_amdgcn_s_setprio(1);
      M1P(0, 0); M1P(1, 0); M1P(2, 0); M1P(3, 0);
      LGKM(4);
      M1(1, 0, 0); M1(1, 1, 0); M1(1, 2, 0); M1(1, 3, 0);
      LGKM(2);
      M1(2, 0, 0); M1(2, 1, 0); M1(2, 2, 0); M1(2, 3, 0);
      LGKM(0);
      M1(3, 0, 0); M1(3, 1, 0); M1(3, 2, 0); M1(3, 3, 0);
      M1P(0, 1); M1P(1, 1); M1P(2, 1); M1P(3, 1);
      M1(1, 0, 1); M1(1, 1, 1); M1(1, 2, 1); M1(1, 3, 1);
      M1(2, 0, 1); M1(2, 1, 1); M1(2, 2, 1); M1(2, 3, 1);
      M1(3, 0, 1); M1(3, 1, 1); M1(3, 2, 1); M1(3, 3, 1);
      __builtin_amdgcn_s_setprio(0);
      if (s2) { asm volatile("s_waitcnt vmcnt(4)" ::: "memory"); }
      else    { asm volatile("s_waitcnt vmcnt(0)" ::: "memory"); }
      __builtin_amdgcn_s_barrier();
    }
  }
#undef STG_A
#undef STG_B
#undef MK
#undef M1P
#undef M1
#undef LD

  // epilogue: C/D layout col=lane&15, row=(lane>>4)*4+reg (m89-verified)
#pragma unroll
  for (int am = 0; am < 8; ++am) {
    const int qm = am >> 2, f = am & 3;
    const int grow0 = m0 + qm * 128 + wm * 64 + f * 16 + l4 * 4;
#pragma unroll
    for (int an = 0; an < 4; ++an) {
      const int gcol = n0 + (an >> 1) * 128 + wn * 32 + (an & 1) * 16 + l15;
      float bc = 0.f;
      if (BIAS_MODE == 1) bc = bias[gcol];
#pragma unroll
      for (int r = 0; r < 4; ++r) {
        float bv_ = (BIAS_MODE == 2) ? bias[grow0 + r] : bc;
        float v = acc[am][an][r] * alpha + bv_;
        long long idx = cbase + (long long)(grow0 + r) * ldc + gcol;
        if constexpr (OUT_BF16) ((u16*)Cv)[idx] = f2bf(v);
        else                    ((float*)Cv)[idx] = v;
      }
    }
  }
}

// ---- standalone batched NT GEMM (scores / outputs), XCD-swizzled ----
template <bool OUT_BF16>
__global__ __launch_bounds__(512, 2) void k_gemm8(
    const u16* __restrict__ A, const u16* __restrict__ B,
    void* __restrict__ Cv, int K, int lda, int ldb, int ldc,
    long long sA, long long sB, long long sC, float alpha, int gx, int gy) {
  __shared__ alignas(16) u16 lds[65536];   // 128 KiB: As | Bs
  const int nwg = gridDim.x;
  int lin = blockIdx.x;
  lin = (lin & 7) * (nwg >> 3) + (lin >> 3);
  const int gxy = gx * gy;
  const int bz = lin / gxy;
  const int rem = lin - bz * gxy;
  const int by = rem / gx;
  const int bx = rem - by * gx;
  gemm_body<OUT_BF16, 0>(A + (long long)bz * sA, B + (long long)bz * sB, Cv,
                         nullptr, K, lda, ldb, ldc, alpha,
                         by * 256, bx * 256, (long long)bz * sC,
                         lds, lds + 32768);
}

// ---- K2: Q/K projection (256 blk) + V^T projection (128 blk) + X^T (2048) ---
__global__ __launch_bounds__(512, 2) void k_proj(
    const u16* __restrict__ xb, const u16* __restrict__ Wqkv,
    const float* __restrict__ bQK, const float* __restrict__ bv,
    u16* __restrict__ QKb, u16* __restrict__ VTX) {
  __shared__ alignas(16) u16 lds[65536];
  const int bid = blockIdx.x;
  if (bid < 384) {
    int lin = (bid & 7) * 48 + (bid >> 3);    // bijective on [0,384)
    if (lin < 256) {            // Q/K-proj: M=8192 (gy=32), N=2048 (gx=8)
      const int by = lin >> 3, bx = lin & 7;
      gemm_body<true, 1>(xb, Wqkv, QKb, bQK, 1024, 1024, 1024, 2048, 1.0f,
                         by * 256, bx * 256, 0, lds, lds + 32768);
    } else {                    // V^T-proj: M=1024 (gy=4), N=8192 (gx=32)
      const int l2 = lin - 256;
      const int by = l2 >> 5, bx = l2 & 31;
      gemm_body<true, 2>(Wqkv + 2048 * 1024, xb, VTX, bv, 1024, 1024, 1024,
                         16384, 1.0f, by * 256, bx * 256, 0, lds, lds + 32768);
    }
  } else {                      // X^T: 64x64 tiles, 2048 blocks
    const int tb = bid - 384;
    const int r0 = (tb >> 4) * 64, c0 = (tb & 15) * 64;   // row/col in x
    const int tx = threadIdx.x & 63, ty = threadIdx.x >> 6;
    u16* tile = lds;            // [64][65]
#pragma unroll
    for (int i = 0; i < 64; i += 8)
      tile[(ty + i) * 65 + tx] = xb[(long long)(r0 + ty + i) * 1024 + c0 + tx];
    __syncthreads();
#pragma unroll
    for (int i = 0; i < 64; i += 8)
      VTX[(long long)(c0 + ty + i) * 16384 + 8192 + r0 + tx] = tile[tx * 65 + ty + i];
  }
}

// ==== fused softmax + transpose: P (raw scores) -> P normalized (in place)
// ==== AND PT normalized.  128 blocks x 512 thr; block owns 64 rows of P.
__global__ __launch_bounds__(512) void k_smt(u16* __restrict__ P,
                                             u16* __restrict__ PT) {
  __shared__ float sm_m[64], sm_il[64];
  __shared__ u16 tile[64 * 65];
  const int bb = blockIdx.x;                  // 0..127
  const long long r0g = (long long)bb * 64;   // global q-row
  const int b = bb >> 5;                      // batch (32 blocks/batch)
  const int q0 = (bb & 31) * 64;
  u16* Pr = P + r0g * 2048;
  u16* PTb = PT + (long long)b * 2048 * 2048;
  const int t = threadIdx.x;

  // phase 1: per-row max & sumexp (online), 8 threads per row, 256 cols each
  {
    const int r = t >> 3, c8 = t & 7;
    const u16* prow = Pr + (long long)r * 2048 + c8 * 8;
    float m = -3.0e38f, s = 0.f;
    for (int j = 0; j < 32; ++j) {
      us8 v = *reinterpret_cast<const us8*>(prow + (long long)j * 64);
      float f[8];
#pragma unroll
      for (int e = 0; e < 8; ++e) f[e] = bf2f(v[e]);
      float mc = f[0];
#pragma unroll
      for (int e = 1; e < 8; ++e) mc = fmaxf(mc, f[e]);
      float mn = fmaxf(m, mc);
      float sc = 0.f;
#pragma unroll
      for (int e = 0; e < 8; ++e) sc += __expf(f[e] - mn);
      s = s * __expf(m - mn) + sc;
      m = mn;
    }
#pragma unroll
    for (int o = 1; o < 8; o <<= 1) {
      float mo = __shfl_xor(m, o), so = __shfl_xor(s, o);
      float mn = fmaxf(m, mo);
      s = s * __expf(m - mn) + so * __expf(mo - mn);
      m = mn;
    }
    if (c8 == 0) { sm_m[r] = m; sm_il[r] = 1.0f / s; }
  }
  __syncthreads();

  // phase 2: per 64x64 col-tile: normalize (write P) + transpose (write PT)
  const int tx = t & 63, ty = t >> 6;         // ty 0..7
  for (int ct = 0; ct < 32; ++ct) {
    const int c0 = ct * 64;
#pragma unroll
    for (int i = 0; i < 64; i += 8) {
      const int rl = i + ty;
      const long long idx = (long long)rl * 2048 + c0 + tx;
      float e = __expf(bf2f(Pr[idx]) - sm_m[rl]) * sm_il[rl];
      u16 o = f2bf(e);
      Pr[idx] = o;
      tile[rl * 65 + tx] = o;
    }
    __syncthreads();
#pragma unroll
    for (int i = 0; i < 64; i += 8) {
      const int kl = i + ty;
      PTb[(long long)(c0 + kl) * 2048 + q0 + tx] = tile[tx * 65 + kl];
    }
    __syncthreads();
  }
}

extern "C" void kernel_launch(void* const* d_in, const int* in_sizes, int n_in,
                              void* d_out, int out_size, void* d_ws, size_t ws_size,
                              hipStream_t stream) {
  (void)in_sizes; (void)n_in; (void)out_size;
  const float* x  = (const float*)d_in[0];
  const float* Wq = (const float*)d_in[1];
  const float* bq = (const float*)d_in[2];
  const float* Wk = (const float*)d_in[3];
  const float* bk = (const float*)d_in[4];
  const float* Wv = (const float*)d_in[5];
  const float* bv = (const float*)d_in[6];
  float* out = (float*)d_out;

  const int B = 4, S = 2048, D = 1024;
  const long long MX = (long long)B * S;  // 8192

  const long long need = MX * D * 2              // xb
                       + 3LL * D * D * 2         // Wqkv (contiguous after xb)
                       + 2048 * 4                // bQK
                       + MX * 2 * D * 2          // QKb [8192][2048]
                       + 2LL * B * S * S * 2     // P, PT (adjacent)
                       + (long long)D * 16384 * 2; // VTX [1024][16384]
  if ((long long)ws_size < need) return;

  char* w = (char*)d_ws;
  u16*   xb   = (u16*)w;   w += MX * D * 2;
  u16*   Wqkv = (u16*)w;   w += 3LL * D * D * 2;  // = xb + MX*D (contiguous)
  float* bQK  = (float*)w; w += 2048 * 4;
  u16*   QKb  = (u16*)w;   w += MX * 2 * D * 2;
  u16*   P    = (u16*)w;   w += (long long)B * S * S * 2;
  u16*   PT   = (u16*)w;   w += (long long)B * S * S * 2;   // = P + 4*S*S
  u16*   VTX  = (u16*)w;   w += (long long)D * 16384 * 2;
  (void)Wqkv;

  dim3 blk256(256), blk512(512);

  // K1: fused converts (xb+Wqkv contiguous) + bias concat (bq|bk -> bQK)
  {
    int xn4 = (int)(MX * D / 4);          // 2097152
    int wn4 = D * D / 4;                  // 262144
    int tot = xn4 + 3 * wn4 + 512;        // + 512 float4 bias units
    k_cvt_all<<<dim3((tot + 255) / 256), blk256, 0, stream>>>(
        x, Wq, Wk, Wv, bq, bk, xb, bQK, xn4, wn4);
  }

  // K2: QK-proj + VT-proj + X^T   (384 GEMM blocks + 2048 transpose blocks)
  k_proj<<<dim3(384 + 2048), blk512, 0, stream>>>(xb, Wqkv, bQK, bv, QKb, VTX);

  // K3: S = (Q @ K^T)/32 per batch: M=N=2048, K=1024 -> P bf16 (raw scores)
  k_gemm8<true><<<dim3(256), blk512, 0, stream>>>(
      QKb, QKb + D, P, D, 2 * D, 2 * D, S,
      (long long)S * 2 * D, (long long)S * 2 * D, (long long)S * S, 0.03125f, 8, 8);

  // K4: fused softmax + transpose -> P (normalized, in place) + PT
  k_smt<<<dim3(128), blk512, 0, stream>>>(P, PT);

  // K5: merged z<4 -> out1[z] = NT(P_z, VT_z); z>=4 -> out2[z-4] = NT(PT, XT)
  // A = P + z*S*S (PT contiguous); B = VTX + z*2048 (XT = cols 8192+)
  k_gemm8<false><<<dim3(256), blk512, 0, stream>>>(
      P, VTX, out, S, S, 16384, D,
      (long long)S * S, 2048, (long long)S * D, 1.0f, 4, 8);
}

// Round 10
// 196.118 us; speedup vs baseline: 1.1240x; 1.1240x over previous
//
#include <hip/hip_runtime.h>
#include <hip/hip_bf16.h>
#include <stdint.h>

typedef unsigned short u16;
typedef u16   us8    __attribute__((ext_vector_type(8)));
typedef __bf16 bf16x8 __attribute__((ext_vector_type(8)));
typedef float f32x4  __attribute__((ext_vector_type(4)));

#define DEV static __device__ __forceinline__

DEV u16 f2bf(float f) {                       // fp32 -> bf16 RNE
  uint32_t u = __builtin_bit_cast(uint32_t, f);
  u += 0x7FFFu + ((u >> 16) & 1u);
  return (u16)(u >> 16);
}
DEV float bf2f(u16 s) { return __builtin_bit_cast(float, (uint32_t)s << 16); }

DEV void gl16(const void* g, void* l) {       // async global->LDS, 16B/lane
  __builtin_amdgcn_global_load_lds((const __attribute__((address_space(1))) void*)g,
                                   (__attribute__((address_space(3))) void*)l, 16, 0, 0);
}

// ------- fused fp32 -> bf16 convert for x, Wq, Wk, Wv + bias concat -------
__global__ __launch_bounds__(256) void k_cvt_all(
    const float* __restrict__ x, const float* __restrict__ wq,
    const float* __restrict__ wk, const float* __restrict__ wv,
    const float* __restrict__ bq, const float* __restrict__ bk,
    u16* __restrict__ out, float* __restrict__ bQK, int xn4, int wn4) {
  int i = blockIdx.x * 256 + threadIdx.x;
  const int cvt_tot = xn4 + 3 * wn4;
  if (i < cvt_tot) {
    const float* src;
    int idx;
    if (i < xn4) { src = x; idx = i; }
    else {
      int j = i - xn4;
      if (j < wn4) { src = wq; idx = j; }
      else if (j < 2 * wn4) { src = wk; idx = j - wn4; }
      else { src = wv; idx = j - 2 * wn4; }
    }
    float4 v = reinterpret_cast<const float4*>(src)[idx];
    uint2 o;
    o.x = (uint32_t)f2bf(v.x) | ((uint32_t)f2bf(v.y) << 16);
    o.y = (uint32_t)f2bf(v.z) | ((uint32_t)f2bf(v.w) << 16);
    reinterpret_cast<uint2*>(out)[i] = o;
  } else {
    int j = i - cvt_tot;                 // bias copy: bq(256 f4) bk(256 f4)
    if (j < 256)      reinterpret_cast<float4*>(bQK)[j] = reinterpret_cast<const float4*>(bq)[j];
    else if (j < 512) reinterpret_cast<float4*>(bQK)[j] = reinterpret_cast<const float4*>(bk)[j - 256];
  }
}

// =================== 256x256-tile 2-phase NT GEMM body (R7, proven) ==========
// 2 phases/K-tile split by A-half, B-frags held in regs, stage PH0->A1B1(t+1),
// PH1->A0B0(t+2), boundary vmcnt(4), counted-lgkm clusters, k-major MFMA,
// XOR swizzle + inverse-swizzled gl16 source.
#define SB0 __builtin_amdgcn_sched_barrier(0)
#define LGKM(N) do { asm volatile("s_waitcnt lgkmcnt(" #N ")" ::: "memory"); \
                     __builtin_amdgcn_sched_barrier(0); } while (0)

template <bool OUT_BF16, int BIAS_MODE>
DEV void gemm_body(const u16* __restrict__ A, const u16* __restrict__ B,
                   void* __restrict__ Cv, const float* __restrict__ bias,
                   int K, int lda, int ldb, int ldc, float alpha,
                   int m0, int n0, long long cbase, u16* AsB, u16* BsB) {
  const int t = threadIdx.x;
  const int lane = t & 63;
  const int wid = t >> 6;
  const int wm = wid >> 2;       // 0..1
  const int wn = wid & 3;        // 0..3
  const int l15 = lane & 15, l4 = lane >> 4;

  const int prow = t >> 3;
  const int scol = ((t & 7) ^ (prow & 7)) * 8;
  const u16* Abase = A + (long long)(m0 + prow) * lda + scol;
  const u16* Bbase = B + (long long)(n0 + prow) * ldb + scol;
  const long long a64 = (long long)64 * lda, a128 = (long long)128 * lda;
  const long long b64 = (long long)64 * ldb, b128 = (long long)128 * ldb;
  u16* AsT = AsB + t * 8;
  u16* BsT = BsB + t * 8;

#define STG_A(h, kt) { const u16* s_ = Abase + (h) * a128 + (long long)(kt) * 64; \
    u16* d_ = AsT + (((kt) & 1) * 2 + (h)) * 8192; gl16(s_, d_); gl16(s_ + a64, d_ + 4096); }
#define STG_B(h, kt) { const u16* s_ = Bbase + (h) * b128 + (long long)(kt) * 64; \
    u16* d_ = BsT + (((kt) & 1) * 2 + (h)) * 8192; gl16(s_, d_); gl16(s_ + b64, d_ + 4096); }

  const int aro = wm * 64 + l15;
  const int bro = wn * 32 + l15;
  const int cs0 = ((l4) ^ (l15 & 7)) * 8;
  const int cs1 = ((4 + l4) ^ (l15 & 7)) * 8;
#define LD(base, row, cs) (*(const bf16x8*)&(base)[(row) * 64 + (cs)])

  f32x4 acc[8][4];
#pragma unroll
  for (int i = 0; i < 8; ++i)
#pragma unroll
    for (int j = 0; j < 4; ++j) { f32x4 z = {0.f, 0.f, 0.f, 0.f}; acc[i][j] = z; }

  const int NT = K >> 6;

  STG_A(0, 0); STG_A(1, 0); STG_B(0, 0); STG_B(1, 0);
  STG_A(0, 1); STG_B(0, 1);
  asm volatile("s_waitcnt vmcnt(4)" ::: "memory");
  __builtin_amdgcn_s_barrier();

#define MK(f_, fn_, k_)                                                         \
  acc[f_][fn_] = __builtin_amdgcn_mfma_f32_16x16x32_bf16(af[f_][k_], bfr[fn_][k_], acc[f_][fn_], 0, 0, 0)
#define M1P(fn_, k_)                                                            \
  acc[4][fn_] = __builtin_amdgcn_mfma_f32_16x16x32_bf16(a1[k_], bfr[fn_][k_], acc[4][fn_], 0, 0, 0)
#define M1(f_, fn_, k_)                                                         \
  acc[4 + (f_)][fn_] = __builtin_amdgcn_mfma_f32_16x16x32_bf16(af1[(f_) - 1][k_], bfr[fn_][k_], acc[4 + (f_)][fn_], 0, 0, 0)

  for (int tt = 0; tt < NT; ++tt) {
    const int p = tt & 1;
    const bool s1 = (tt + 1 < NT);
    const bool s2 = (tt + 2 < NT);
    bf16x8 bfr[4][2];
    bf16x8 a1[2];

    // ---------------- PH0: qm = 0 ----------------
    {
      const u16* Ah  = AsB + (p * 2) * 8192;
      const u16* Ah1 = AsB + (p * 2 + 1) * 8192;
      const u16* Bh0 = BsB + (p * 2) * 8192;
      const u16* Bh1 = BsB + (p * 2 + 1) * 8192;
      bf16x8 af[4][2];
      bfr[0][0] = LD(Bh0, bro, cs0);      bfr[0][1] = LD(Bh0, bro, cs1);
      bfr[1][0] = LD(Bh0, bro + 16, cs0); bfr[1][1] = LD(Bh0, bro + 16, cs1);
      af[0][0]  = LD(Ah, aro, cs0);       af[0][1]  = LD(Ah, aro, cs1);
      SB0;
      bfr[2][0] = LD(Bh1, bro, cs0);      bfr[2][1] = LD(Bh1, bro, cs1);
      bfr[3][0] = LD(Bh1, bro + 16, cs0); bfr[3][1] = LD(Bh1, bro + 16, cs1);
      af[1][0]  = LD(Ah, aro + 16, cs0);  af[1][1]  = LD(Ah, aro + 16, cs1);
      SB0;
      af[2][0] = LD(Ah, aro + 32, cs0);   af[2][1] = LD(Ah, aro + 32, cs1);
      SB0;
      af[3][0] = LD(Ah, aro + 48, cs0);   af[3][1] = LD(Ah, aro + 48, cs1);
      if (s1) { STG_A(1, tt + 1); STG_B(1, tt + 1); }
      SB0;
      a1[0] = LD(Ah1, aro, cs0);          a1[1] = LD(Ah1, aro, cs1);
      SB0;
      LGKM(12);
      __builtin_amdgcn_s_setprio(1);
      MK(0, 0, 0); MK(0, 1, 0);
      LGKM(6);
      MK(0, 2, 0); MK(0, 3, 0);
      MK(1, 0, 0); MK(1, 1, 0); MK(1, 2, 0); MK(1, 3, 0);
      LGKM(4);
      MK(2, 0, 0); MK(2, 1, 0); MK(2, 2, 0); MK(2, 3, 0);
      LGKM(2);
      MK(3, 0, 0); MK(3, 1, 0); MK(3, 2, 0); MK(3, 3, 0);
      MK(0, 0, 1); MK(0, 1, 1); MK(0, 2, 1); MK(0, 3, 1);
      MK(1, 0, 1); MK(1, 1, 1); MK(1, 2, 1); MK(1, 3, 1);
      MK(2, 0, 1); MK(2, 1, 1); MK(2, 2, 1); MK(2, 3, 1);
      MK(3, 0, 1); MK(3, 1, 1); MK(3, 2, 1); MK(3, 3, 1);
      __builtin_amdgcn_s_setprio(0);
      __builtin_amdgcn_s_barrier();
    }

    // ---------------- PH1: qm = 1 (bfr + a1 held in registers) ----------------
    {
      const u16* Ah1 = AsB + (p * 2 + 1) * 8192;
      bf16x8 af1[3][2];
      af1[0][0] = LD(Ah1, aro + 16, cs0); af1[0][1] = LD(Ah1, aro + 16, cs1);
      SB0;
      af1[1][0] = LD(Ah1, aro + 32, cs0); af1[1][1] = LD(Ah1, aro + 32, cs1);
      SB0;
      af1[2][0] = LD(Ah1, aro + 48, cs0); af1[2][1] = LD(Ah1, aro + 48, cs1);
      if (s2) { STG_A(0, tt + 2); STG_B(0, tt + 2); }
      SB0;
      LGKM(6);
      __builtin_amdgcn_s_setprio(1);
      M1P(0, 0); M1P(1, 0); M1P(2, 0); M1P(3, 0);
      LGKM(4);
      M1(1, 0, 0); M1(1, 1, 0); M1(1, 2, 0); M1(1, 3, 0);
      LGKM(2);
      M1(2, 0, 0); M1(2, 1, 0); M1(2, 2, 0); M1(2, 3, 0);
      LGKM(0);
      M1(3, 0, 0); M1(3, 1, 0); M1(3, 2, 0); M1(3, 3, 0);
      M1P(0, 1); M1P(1, 1); M1P(2, 1); M1P(3, 1);
      M1(1, 0, 1); M1(1, 1, 1); M1(1, 2, 1); M1(1, 3, 1);
      M1(2, 0, 1); M1(2, 1, 1); M1(2, 2, 1); M1(2, 3, 1);
      M1(3, 0, 1); M1(3, 1, 1); M1(3, 2, 1); M1(3, 3, 1);
      __builtin_amdgcn_s_setprio(0);
      if (s2) { asm volatile("s_waitcnt vmcnt(4)" ::: "memory"); }
      else    { asm volatile("s_waitcnt vmcnt(0)" ::: "memory"); }
      __builtin_amdgcn_s_barrier();
    }
  }
#undef STG_A
#undef STG_B
#undef MK
#undef M1P
#undef M1
#undef LD

  // epilogue: C/D layout col=lane&15, row=(lane>>4)*4+reg (m89-verified)
#pragma unroll
  for (int am = 0; am < 8; ++am) {
    const int qm = am >> 2, f = am & 3;
    const int grow0 = m0 + qm * 128 + wm * 64 + f * 16 + l4 * 4;
#pragma unroll
    for (int an = 0; an < 4; ++an) {
      const int gcol = n0 + (an >> 1) * 128 + wn * 32 + (an & 1) * 16 + l15;
      float bc = 0.f;
      if (BIAS_MODE == 1) bc = bias[gcol];
#pragma unroll
      for (int r = 0; r < 4; ++r) {
        float bv_ = (BIAS_MODE == 2) ? bias[grow0 + r] : bc;
        float v = acc[am][an][r] * alpha + bv_;
        long long idx = cbase + (long long)(grow0 + r) * ldc + gcol;
        if constexpr (OUT_BF16) ((u16*)Cv)[idx] = f2bf(v);
        else                    ((float*)Cv)[idx] = v;
      }
    }
  }
}

// ---- standalone batched NT GEMM (outputs), XCD-swizzled ----
template <bool OUT_BF16>
__global__ __launch_bounds__(512, 2) void k_gemm8(
    const u16* __restrict__ A, const u16* __restrict__ B,
    void* __restrict__ Cv, int K, int lda, int ldb, int ldc,
    long long sA, long long sB, long long sC, float alpha, int gx, int gy) {
  __shared__ alignas(16) u16 lds[65536];   // 128 KiB: As | Bs
  const int nwg = gridDim.x;
  int lin = blockIdx.x;
  lin = (lin & 7) * (nwg >> 3) + (lin >> 3);
  const int gxy = gx * gy;
  const int bz = lin / gxy;
  const int rem = lin - bz * gxy;
  const int by = rem / gx;
  const int bx = rem - by * gx;
  gemm_body<OUT_BF16, 0>(A + (long long)bz * sA, B + (long long)bz * sB, Cv,
                         nullptr, K, lda, ldb, ldc, alpha,
                         by * 256, bx * 256, (long long)bz * sC,
                         lds, lds + 32768);
}

// ---- K2': Q/K projection only — 256 blocks = exactly 1 round/CU ----
// QKb[8192][2048] = X @ [Wq;Wk]^T + b.
__global__ __launch_bounds__(512, 2) void k_projQK(
    const u16* __restrict__ xb, const u16* __restrict__ Wqkv,
    const float* __restrict__ bQK, u16* __restrict__ QKb) {
  __shared__ alignas(16) u16 lds[65536];
  int lin = (blockIdx.x & 7) * 32 + (blockIdx.x >> 3);   // bijective on [0,256)
  const int by = lin >> 3, bx = lin & 7;                 // gy=32, gx=8
  gemm_body<true, 1>(xb, Wqkv, QKb, bQK, 1024, 1024, 1024, 2048, 1.0f,
                     by * 256, bx * 256, 0, lds, lds + 32768);
}

// ---- K3': scores (256 blk) + V^T-proj (128 blk) + X^T transpose (2048) ----
// scores: P_z = (Q_z @ K_z^T)/32, raw.  VT-proj: VTX cols 0..8191 = Wv@X^T+bv.
// XT: VTX cols 8192.. = X^T.  VT/XT fill the idle CUs of scores' round 2.
__global__ __launch_bounds__(512, 2) void k_sv(
    const u16* __restrict__ xb, const u16* __restrict__ Wqkv,
    const float* __restrict__ bv, const u16* __restrict__ QKb,
    u16* __restrict__ P, u16* __restrict__ VTX) {
  __shared__ alignas(16) u16 lds[65536];
  const int bid = blockIdx.x;
  if (bid < 384) {
    int lin = (bid & 7) * 48 + (bid >> 3);    // bijective on [0,384)
    if (lin < 256) {            // scores: z = lin>>6, 8x8 tile grid per batch
      const int z = lin >> 6;
      const int rem = lin & 63;
      const int by = rem >> 3, bx = rem & 7;
      const long long qoff = (long long)z * 2048 * 2048;
      gemm_body<true, 0>(QKb + qoff, QKb + 1024 + qoff, P, nullptr,
                         1024, 2048, 2048, 2048, 0.03125f,
                         by * 256, bx * 256, (long long)z * 2048 * 2048,
                         lds, lds + 32768);
    } else {                    // V^T-proj: M=1024 (gy=4), N=8192 (gx=32)
      const int l2 = lin - 256;
      const int by = l2 >> 5, bx = l2 & 31;
      gemm_body<true, 2>(Wqkv + 2048 * 1024, xb, VTX, bv, 1024, 1024, 1024,
                         16384, 1.0f, by * 256, bx * 256, 0, lds, lds + 32768);
    }
  } else {                      // X^T: 64x64 tiles, 2048 blocks
    const int tb = bid - 384;
    const int r0 = (tb >> 4) * 64, c0 = (tb & 15) * 64;   // row/col in x
    const int tx = threadIdx.x & 63, ty = threadIdx.x >> 6;
    u16* tile = lds;            // [64][65]
#pragma unroll
    for (int i = 0; i < 64; i += 8)
      tile[(ty + i) * 65 + tx] = xb[(long long)(r0 + ty + i) * 1024 + c0 + tx];
    __syncthreads();
#pragma unroll
    for (int i = 0; i < 64; i += 8)
      VTX[(long long)(c0 + ty + i) * 16384 + 8192 + r0 + tx] = tile[tx * 65 + ty + i];
  }
}

// ---------------- in-place row softmax over 2048 bf16 cols ----------------
__global__ __launch_bounds__(256) void k_softmax(u16* __restrict__ P) {
  const long long row = blockIdx.x;
  u16* p = P + row * 2048;
  const int t = threadIdx.x;
  us8 v = *reinterpret_cast<const us8*>(&p[t * 8]);
  float f[8];
#pragma unroll
  for (int j = 0; j < 8; ++j) f[j] = bf2f(v[j]);
  float m = f[0];
#pragma unroll
  for (int j = 1; j < 8; ++j) m = fmaxf(m, f[j]);
#pragma unroll
  for (int o = 32; o > 0; o >>= 1) m = fmaxf(m, __shfl_xor(m, o));
  __shared__ float redm[4], reds[4];
  if ((t & 63) == 0) redm[t >> 6] = m;
  __syncthreads();
  m = fmaxf(fmaxf(redm[0], redm[1]), fmaxf(redm[2], redm[3]));
  float s = 0.f;
#pragma unroll
  for (int j = 0; j < 8; ++j) {
    f[j] = __expf(f[j] - m);
    s += f[j];
  }
#pragma unroll
  for (int o = 32; o > 0; o >>= 1) s += __shfl_xor(s, o);
  if ((t & 63) == 0) reds[t >> 6] = s;
  __syncthreads();
  s = reds[0] + reds[1] + reds[2] + reds[3];
  const float inv = 1.0f / s;
  us8 o8;
#pragma unroll
  for (int j = 0; j < 8; ++j) o8[j] = f2bf(f[j] * inv);
  *reinterpret_cast<us8*>(&p[t * 8]) = o8;
}

// ---- 64x64-tile bf16 transpose (square, same ld both sides, z-batched) ----
__global__ __launch_bounds__(512) void k_tr64(const u16* __restrict__ in,
                                              u16* __restrict__ out,
                                              int ld, long long sIO) {
  __shared__ u16 tile[64 * 65];
  const long long base = (long long)blockIdx.z * sIO;
  const int r0 = blockIdx.y * 64, c0 = blockIdx.x * 64;
  const int tx = threadIdx.x & 63, ty = threadIdx.x >> 6;
#pragma unroll
  for (int i = 0; i < 64; i += 8)
    tile[(ty + i) * 65 + tx] = in[base + (long long)(r0 + ty + i) * ld + c0 + tx];
  __syncthreads();
#pragma unroll
  for (int i = 0; i < 64; i += 8)
    out[base + (long long)(c0 + ty + i) * ld + r0 + tx] = tile[tx * 65 + ty + i];
}

extern "C" void kernel_launch(void* const* d_in, const int* in_sizes, int n_in,
                              void* d_out, int out_size, void* d_ws, size_t ws_size,
                              hipStream_t stream) {
  (void)in_sizes; (void)n_in; (void)out_size;
  const float* x  = (const float*)d_in[0];
  const float* Wq = (const float*)d_in[1];
  const float* bq = (const float*)d_in[2];
  const float* Wk = (const float*)d_in[3];
  const float* bk = (const float*)d_in[4];
  const float* Wv = (const float*)d_in[5];
  const float* bv = (const float*)d_in[6];
  float* out = (float*)d_out;

  const int B = 4, S = 2048, D = 1024;
  const long long MX = (long long)B * S;  // 8192

  const long long need = MX * D * 2              // xb
                       + 3LL * D * D * 2         // Wqkv (contiguous after xb)
                       + 2048 * 4                // bQK
                       + MX * 2 * D * 2          // QKb [8192][2048]
                       + 2LL * B * S * S * 2     // P, PT (adjacent)
                       + (long long)D * 16384 * 2; // VTX [1024][16384]
  if ((long long)ws_size < need) return;

  char* w = (char*)d_ws;
  u16*   xb   = (u16*)w;   w += MX * D * 2;
  u16*   Wqkv = (u16*)w;   w += 3LL * D * D * 2;  // = xb + MX*D (contiguous)
  float* bQK  = (float*)w; w += 2048 * 4;
  u16*   QKb  = (u16*)w;   w += MX * 2 * D * 2;
  u16*   P    = (u16*)w;   w += (long long)B * S * S * 2;
  u16*   PT   = (u16*)w;   w += (long long)B * S * S * 2;   // = P + 4*S*S
  u16*   VTX  = (u16*)w;   w += (long long)D * 16384 * 2;
  (void)Wqkv;

  dim3 blk256(256), blk512(512);

  // K1: fused converts (xb+Wqkv contiguous) + bias concat (bq|bk -> bQK)
  {
    int xn4 = (int)(MX * D / 4);          // 2097152
    int wn4 = D * D / 4;                  // 262144
    int tot = xn4 + 3 * wn4 + 512;        // + 512 float4 bias units
    k_cvt_all<<<dim3((tot + 255) / 256), blk256, 0, stream>>>(
        x, Wq, Wk, Wv, bq, bk, xb, bQK, xn4, wn4);
  }

  // K2': QK-proj only — exactly 1 block/CU round
  k_projQK<<<dim3(256), blk512, 0, stream>>>(xb, Wqkv, bQK, QKb);

  // K3': scores (256) + VT-proj (128) + X^T (2048) — VT/XT fill round 2
  k_sv<<<dim3(384 + 2048), blk512, 0, stream>>>(xb, Wqkv, bv, QKb, P, VTX);

  // K4: softmax rows in place (P raw -> normalized)
  k_softmax<<<dim3((int)(B * S)), blk256, 0, stream>>>(P);

  // K5: P -> PT (64x64 tiles)
  k_tr64<<<dim3(32, 32, 4), blk512, 0, stream>>>(P, PT, S, (long long)S * S);

  // K6: merged z<4 -> out1[z] = NT(P_z, VT_z); z>=4 -> out2[z-4] = NT(PT, XT)
  // A = P + z*S*S (PT contiguous); B = VTX + z*2048 (XT = cols 8192+)
  k_gemm8<false><<<dim3(256), blk512, 0, stream>>>(
      P, VTX, out, S, S, 16384, D,
      (long long)S * S, 2048, (long long)S * D, 1.0f, 4, 8);
}

// Round 11
// 192.949 us; speedup vs baseline: 1.1425x; 1.0164x over previous
//
#include <hip/hip_runtime.h>
#include <hip/hip_bf16.h>
#include <stdint.h>

typedef unsigned short u16;
typedef u16   us8    __attribute__((ext_vector_type(8)));
typedef u16   us4    __attribute__((ext_vector_type(4)));
typedef __bf16 bf16x8 __attribute__((ext_vector_type(8)));
typedef float f32x4  __attribute__((ext_vector_type(4)));

#define DEV static __device__ __forceinline__

DEV u16 f2bf(float f) {                       // fp32 -> bf16 RNE
  uint32_t u = __builtin_bit_cast(uint32_t, f);
  u += 0x7FFFu + ((u >> 16) & 1u);
  return (u16)(u >> 16);
}
DEV float bf2f(u16 s) { return __builtin_bit_cast(float, (uint32_t)s << 16); }

DEV void gl16(const void* g, void* l) {       // async global->LDS, 16B/lane
  __builtin_amdgcn_global_load_lds((const __attribute__((address_space(1))) void*)g,
                                   (__attribute__((address_space(3))) void*)l, 16, 0, 0);
}

// ------- fused fp32 -> bf16 convert for x, Wq, Wk, Wv + bias concat -------
__global__ __launch_bounds__(256) void k_cvt_all(
    const float* __restrict__ x, const float* __restrict__ wq,
    const float* __restrict__ wk, const float* __restrict__ wv,
    const float* __restrict__ bq, const float* __restrict__ bk,
    u16* __restrict__ out, float* __restrict__ bQK, int xn4, int wn4) {
  int i = blockIdx.x * 256 + threadIdx.x;
  const int cvt_tot = xn4 + 3 * wn4;
  if (i < cvt_tot) {
    const float* src;
    int idx;
    if (i < xn4) { src = x; idx = i; }
    else {
      int j = i - xn4;
      if (j < wn4) { src = wq; idx = j; }
      else if (j < 2 * wn4) { src = wk; idx = j - wn4; }
      else { src = wv; idx = j - 2 * wn4; }
    }
    float4 v = reinterpret_cast<const float4*>(src)[idx];
    uint2 o;
    o.x = (uint32_t)f2bf(v.x) | ((uint32_t)f2bf(v.y) << 16);
    o.y = (uint32_t)f2bf(v.z) | ((uint32_t)f2bf(v.w) << 16);
    reinterpret_cast<uint2*>(out)[i] = o;
  } else {
    int j = i - cvt_tot;                 // bias copy: bq(256 f4) bk(256 f4)
    if (j < 256)      reinterpret_cast<float4*>(bQK)[j] = reinterpret_cast<const float4*>(bq)[j];
    else if (j < 512) reinterpret_cast<float4*>(bQK)[j] = reinterpret_cast<const float4*>(bk)[j - 256];
  }
}

// =================== 256x256-tile 2-phase NT GEMM body (R7, proven) ==========
// BIAS_MODE: 0 none, 1 col-bias, 2 row-bias, 3 row-SCALE (v*=bias[row]),
// 4 scores-special: E=exp(acc*alpha) -> write E [q][k], E^T [k][q] (b64-packed),
// and deterministic per-block row-sum partials psum[q][8] (LDS-combined).
#define SB0 __builtin_amdgcn_sched_barrier(0)
#define LGKM(N) do { asm volatile("s_waitcnt lgkmcnt(" #N ")" ::: "memory"); \
                     __builtin_amdgcn_sched_barrier(0); } while (0)

template <bool OUT_BF16, int BIAS_MODE>
DEV void gemm_body(const u16* __restrict__ A, const u16* __restrict__ B,
                   void* __restrict__ Cv, const float* __restrict__ bias,
                   int K, int lda, int ldb, int ldc, float alpha,
                   int m0, int n0, long long cbase, u16* AsB, u16* BsB) {
  const int t = threadIdx.x;
  const int lane = t & 63;
  const int wid = t >> 6;
  const int wm = wid >> 2;       // 0..1
  const int wn = wid & 3;        // 0..3
  const int l15 = lane & 15, l4 = lane >> 4;

  const int prow = t >> 3;
  const int scol = ((t & 7) ^ (prow & 7)) * 8;
  const u16* Abase = A + (long long)(m0 + prow) * lda + scol;
  const u16* Bbase = B + (long long)(n0 + prow) * ldb + scol;
  const long long a64 = (long long)64 * lda, a128 = (long long)128 * lda;
  const long long b64 = (long long)64 * ldb, b128 = (long long)128 * ldb;
  u16* AsT = AsB + t * 8;
  u16* BsT = BsB + t * 8;

#define STG_A(h, kt) { const u16* s_ = Abase + (h) * a128 + (long long)(kt) * 64; \
    u16* d_ = AsT + (((kt) & 1) * 2 + (h)) * 8192; gl16(s_, d_); gl16(s_ + a64, d_ + 4096); }
#define STG_B(h, kt) { const u16* s_ = Bbase + (h) * b128 + (long long)(kt) * 64; \
    u16* d_ = BsT + (((kt) & 1) * 2 + (h)) * 8192; gl16(s_, d_); gl16(s_ + b64, d_ + 4096); }

  const int aro = wm * 64 + l15;
  const int bro = wn * 32 + l15;
  const int cs0 = ((l4) ^ (l15 & 7)) * 8;
  const int cs1 = ((4 + l4) ^ (l15 & 7)) * 8;
#define LD(base, row, cs) (*(const bf16x8*)&(base)[(row) * 64 + (cs)])

  f32x4 acc[8][4];
#pragma unroll
  for (int i = 0; i < 8; ++i)
#pragma unroll
    for (int j = 0; j < 4; ++j) { f32x4 z = {0.f, 0.f, 0.f, 0.f}; acc[i][j] = z; }

  const int NT = K >> 6;

  STG_A(0, 0); STG_A(1, 0); STG_B(0, 0); STG_B(1, 0);
  STG_A(0, 1); STG_B(0, 1);
  asm volatile("s_waitcnt vmcnt(4)" ::: "memory");
  __builtin_amdgcn_s_barrier();

#define MK(f_, fn_, k_)                                                         \
  acc[f_][fn_] = __builtin_amdgcn_mfma_f32_16x16x32_bf16(af[f_][k_], bfr[fn_][k_], acc[f_][fn_], 0, 0, 0)
#define M1P(fn_, k_)                                                            \
  acc[4][fn_] = __builtin_amdgcn_mfma_f32_16x16x32_bf16(a1[k_], bfr[fn_][k_], acc[4][fn_], 0, 0, 0)
#define M1(f_, fn_, k_)                                                         \
  acc[4 + (f_)][fn_] = __builtin_amdgcn_mfma_f32_16x16x32_bf16(af1[(f_) - 1][k_], bfr[fn_][k_], acc[4 + (f_)][fn_], 0, 0, 0)

  for (int tt = 0; tt < NT; ++tt) {
    const int p = tt & 1;
    const bool s1 = (tt + 1 < NT);
    const bool s2 = (tt + 2 < NT);
    bf16x8 bfr[4][2];
    bf16x8 a1[2];

    // ---------------- PH0: qm = 0 ----------------
    {
      const u16* Ah  = AsB + (p * 2) * 8192;
      const u16* Ah1 = AsB + (p * 2 + 1) * 8192;
      const u16* Bh0 = BsB + (p * 2) * 8192;
      const u16* Bh1 = BsB + (p * 2 + 1) * 8192;
      bf16x8 af[4][2];
      bfr[0][0] = LD(Bh0, bro, cs0);      bfr[0][1] = LD(Bh0, bro, cs1);
      bfr[1][0] = LD(Bh0, bro + 16, cs0); bfr[1][1] = LD(Bh0, bro + 16, cs1);
      af[0][0]  = LD(Ah, aro, cs0);       af[0][1]  = LD(Ah, aro, cs1);
      SB0;
      bfr[2][0] = LD(Bh1, bro, cs0);      bfr[2][1] = LD(Bh1, bro, cs1);
      bfr[3][0] = LD(Bh1, bro + 16, cs0); bfr[3][1] = LD(Bh1, bro + 16, cs1);
      af[1][0]  = LD(Ah, aro + 16, cs0);  af[1][1]  = LD(Ah, aro + 16, cs1);
      SB0;
      af[2][0] = LD(Ah, aro + 32, cs0);   af[2][1] = LD(Ah, aro + 32, cs1);
      SB0;
      af[3][0] = LD(Ah, aro + 48, cs0);   af[3][1] = LD(Ah, aro + 48, cs1);
      if (s1) { STG_A(1, tt + 1); STG_B(1, tt + 1); }
      SB0;
      a1[0] = LD(Ah1, aro, cs0);          a1[1] = LD(Ah1, aro, cs1);
      SB0;
      LGKM(12);
      __builtin_amdgcn_s_setprio(1);
      MK(0, 0, 0); MK(0, 1, 0);
      LGKM(6);
      MK(0, 2, 0); MK(0, 3, 0);
      MK(1, 0, 0); MK(1, 1, 0); MK(1, 2, 0); MK(1, 3, 0);
      LGKM(4);
      MK(2, 0, 0); MK(2, 1, 0); MK(2, 2, 0); MK(2, 3, 0);
      LGKM(2);
      MK(3, 0, 0); MK(3, 1, 0); MK(3, 2, 0); MK(3, 3, 0);
      MK(0, 0, 1); MK(0, 1, 1); MK(0, 2, 1); MK(0, 3, 1);
      MK(1, 0, 1); MK(1, 1, 1); MK(1, 2, 1); MK(1, 3, 1);
      MK(2, 0, 1); MK(2, 1, 1); MK(2, 2, 1); MK(2, 3, 1);
      MK(3, 0, 1); MK(3, 1, 1); MK(3, 2, 1); MK(3, 3, 1);
      __builtin_amdgcn_s_setprio(0);
      __builtin_amdgcn_s_barrier();
    }

    // ---------------- PH1: qm = 1 (bfr + a1 held in registers) ----------------
    {
      const u16* Ah1 = AsB + (p * 2 + 1) * 8192;
      bf16x8 af1[3][2];
      af1[0][0] = LD(Ah1, aro + 16, cs0); af1[0][1] = LD(Ah1, aro + 16, cs1);
      SB0;
      af1[1][0] = LD(Ah1, aro + 32, cs0); af1[1][1] = LD(Ah1, aro + 32, cs1);
      SB0;
      af1[2][0] = LD(Ah1, aro + 48, cs0); af1[2][1] = LD(Ah1, aro + 48, cs1);
      if (s2) { STG_A(0, tt + 2); STG_B(0, tt + 2); }
      SB0;
      LGKM(6);
      __builtin_amdgcn_s_setprio(1);
      M1P(0, 0); M1P(1, 0); M1P(2, 0); M1P(3, 0);
      LGKM(4);
      M1(1, 0, 0); M1(1, 1, 0); M1(1, 2, 0); M1(1, 3, 0);
      LGKM(2);
      M1(2, 0, 0); M1(2, 1, 0); M1(2, 2, 0); M1(2, 3, 0);
      LGKM(0);
      M1(3, 0, 0); M1(3, 1, 0); M1(3, 2, 0); M1(3, 3, 0);
      M1P(0, 1); M1P(1, 1); M1P(2, 1); M1P(3, 1);
      M1(1, 0, 1); M1(1, 1, 1); M1(1, 2, 1); M1(1, 3, 1);
      M1(2, 0, 1); M1(2, 1, 1); M1(2, 2, 1); M1(2, 3, 1);
      M1(3, 0, 1); M1(3, 1, 1); M1(3, 2, 1); M1(3, 3, 1);
      __builtin_amdgcn_s_setprio(0);
      if (s2) { asm volatile("s_waitcnt vmcnt(4)" ::: "memory"); }
      else    { asm volatile("s_waitcnt vmcnt(0)" ::: "memory"); }
      __builtin_amdgcn_s_barrier();
    }
  }
#undef STG_A
#undef STG_B
#undef MK
#undef M1P
#undef M1
#undef LD

  // ======= epilogue: C/D layout col=lane&15, row=(lane>>4)*4+reg =======
  if constexpr (BIAS_MODE == 4) {
    // scores-special: E = exp(acc*alpha); dual-write E [q][k] and E^T [k][q]
    // (b64-packed: 4 consecutive rows, same col); deterministic row-sum
    // partials via LDS combine -> psum[gq*8 + bx].  ldc==2048 assumed.
    u16* Cb = (u16*)Cv;
    float* psum = const_cast<float*>(bias);
    float* lds_ps = (float*)AsB;          // [256][4] fp32 (LDS free after loop)
#pragma unroll
    for (int am = 0; am < 8; ++am) {
      const int qm = am >> 2, f = am & 3;
      const int lrow0 = qm * 128 + wm * 64 + f * 16 + l4 * 4;   // 0..255
      float rp[4] = {0.f, 0.f, 0.f, 0.f};
#pragma unroll
      for (int an = 0; an < 4; ++an) {
        const int gcol = n0 + (an >> 1) * 128 + wn * 32 + (an & 1) * 16 + l15;
        us4 et;
#pragma unroll
        for (int r = 0; r < 4; ++r) {
          float e = __expf(acc[am][an][r] * alpha);
          rp[r] += e;
          u16 h = f2bf(e);
          Cb[cbase + (long long)(m0 + lrow0 + r) * 2048 + gcol] = h;
          et[r] = h;
        }
        *(us4*)&Cb[cbase + 4LL * 2048 * 2048 + (long long)gcol * 2048 + (m0 + lrow0)] = et;
      }
#pragma unroll
      for (int r = 0; r < 4; ++r) {
        float v = rp[r];
        v += __shfl_xor(v, 1); v += __shfl_xor(v, 2);
        v += __shfl_xor(v, 4); v += __shfl_xor(v, 8);
        if (l15 == 0) lds_ps[(lrow0 + r) * 4 + wn] = v;
      }
    }
    __syncthreads();
    if (t < 256) {
      float s = lds_ps[t * 4] + lds_ps[t * 4 + 1] + lds_ps[t * 4 + 2] + lds_ps[t * 4 + 3];
      const long long gq = (cbase >> 11) + m0 + t;   // z*2048 + m0 + t
      psum[gq * 8 + (n0 >> 8)] = s;
    }
    return;
  }
#pragma unroll
  for (int am = 0; am < 8; ++am) {
    const int qm = am >> 2, f = am & 3;
    const int grow0 = m0 + qm * 128 + wm * 64 + f * 16 + l4 * 4;
#pragma unroll
    for (int an = 0; an < 4; ++an) {
      const int gcol = n0 + (an >> 1) * 128 + wn * 32 + (an & 1) * 16 + l15;
      float bc = 0.f;
      if (BIAS_MODE == 1) bc = bias[gcol];
#pragma unroll
      for (int r = 0; r < 4; ++r) {
        float v = acc[am][an][r] * alpha;
        if (BIAS_MODE == 1) v += bc;
        if (BIAS_MODE == 2) v += bias[grow0 + r];
        if (BIAS_MODE == 3) v *= bias[grow0 + r];
        long long idx = cbase + (long long)(grow0 + r) * ldc + gcol;
        if constexpr (OUT_BF16) ((u16*)Cv)[idx] = f2bf(v);
        else                    ((float*)Cv)[idx] = v;
      }
    }
  }
}

// ---- K2': Q/K projection — 256 blocks = exactly 1 round/CU ----
__global__ __launch_bounds__(512, 2) void k_projQK(
    const u16* __restrict__ xb, const u16* __restrict__ Wqkv,
    const float* __restrict__ bQK, u16* __restrict__ QKb) {
  __shared__ alignas(16) u16 lds[65536];
  int lin = (blockIdx.x & 7) * 32 + (blockIdx.x >> 3);   // bijective on [0,256)
  const int by = lin >> 3, bx = lin & 7;                 // gy=32, gx=8
  gemm_body<true, 1>(xb, Wqkv, QKb, bQK, 1024, 1024, 1024, 2048, 1.0f,
                     by * 256, bx * 256, 0, lds, lds + 32768);
}

// ---- K3': scores->E,E^T,psum (256 blk) + V^T-proj (128 blk) ----
__global__ __launch_bounds__(512, 2) void k_sc(
    const u16* __restrict__ xb, const u16* __restrict__ Wqkv,
    const float* __restrict__ bv, const u16* __restrict__ QKb,
    u16* __restrict__ E, u16* __restrict__ VTX, float* __restrict__ psum) {
  __shared__ alignas(16) u16 lds[65536];
  int lin = (blockIdx.x & 7) * 48 + (blockIdx.x >> 3);   // bijective on [0,384)
  if (lin < 256) {            // scores: z = lin>>6, 8x8 tile grid per batch
    const int z = lin >> 6;
    const int rem = lin & 63;
    const int by = rem >> 3, bx = rem & 7;
    const long long qoff = (long long)z * 2048 * 2048;
    gemm_body<true, 4>(QKb + qoff, QKb + 1024 + qoff, E, (const float*)psum,
                       1024, 2048, 2048, 2048, 0.03125f,
                       by * 256, bx * 256, (long long)z * 2048 * 2048,
                       lds, lds + 32768);
  } else {                    // V^T-proj: M=1024 (gy=4), N=8192 (gx=32)
    const int l2 = lin - 256;
    const int by = l2 >> 5, bx = l2 & 31;
    gemm_body<true, 2>(Wqkv + 2048 * 1024, xb, VTX, bv, 1024, 1024, 1024,
                       16384, 1.0f, by * 256, bx * 256, 0, lds, lds + 32768);
  }
}

// ---- K4': il = 1/rowsum from psum; X~T = il-scaled X^T into VTX cols 8192+;
// ---- also writes il array (blocks with c0==0). 2048 blocks x 256 thr.
__global__ __launch_bounds__(256) void k_xt(
    const u16* __restrict__ xb, const float* __restrict__ psum,
    float* __restrict__ il_arr, u16* __restrict__ VTX) {
  __shared__ u16 tile[64 * 65];
  __shared__ float lds_il[64];
  const int tb = blockIdx.x;
  const int r0 = (tb >> 4) * 64;   // global q
  const int c0 = (tb & 15) * 64;   // d
  const int t = threadIdx.x;
  if (t < 64) {
    const float* pp = psum + (long long)(r0 + t) * 8;
    float s = pp[0] + pp[1] + pp[2] + pp[3] + pp[4] + pp[5] + pp[6] + pp[7];
    float iv = 1.0f / s;
    lds_il[t] = iv;
    if (c0 == 0) il_arr[r0 + t] = iv;
  }
  __syncthreads();
  const int tx = t & 63, ty = t >> 6;  // ty 0..3
#pragma unroll
  for (int i = 0; i < 64; i += 4)
    tile[(ty + i) * 65 + tx] =
        f2bf(bf2f(xb[(long long)(r0 + ty + i) * 1024 + c0 + tx]) * lds_il[ty + i]);
  __syncthreads();
#pragma unroll
  for (int i = 0; i < 64; i += 4)
    VTX[(long long)(c0 + ty + i) * 16384 + 8192 + r0 + tx] = tile[tx * 65 + ty + i];
}

// ---- K5': outputs. z<4: out1 = il-rowscale( NT(E_z, VT_z) );
// ----       z>=4: out2 = NT(ET_z, X~T_z).  256 blocks.
__global__ __launch_bounds__(512, 2) void k_out(
    const u16* __restrict__ E, const u16* __restrict__ VTX,
    float* __restrict__ out, const float* __restrict__ il) {
  __shared__ alignas(16) u16 lds[65536];
  int lin = (blockIdx.x & 7) * 32 + (blockIdx.x >> 3);   // bijective on [0,256)
  const int bz = lin >> 5;
  const int rem = lin & 31;
  const int by = rem >> 2, bx = rem & 3;   // gy=8, gx=4
  if (bz < 4)
    gemm_body<false, 3>(E + (long long)bz * 2048 * 2048, VTX + (long long)bz * 2048,
                        out, il + bz * 2048, 2048, 2048, 16384, 1024, 1.0f,
                        by * 256, bx * 256, (long long)bz * 2048 * 1024,
                        lds, lds + 32768);
  else
    gemm_body<false, 0>(E + (long long)bz * 2048 * 2048, VTX + (long long)bz * 2048,
                        out, nullptr, 2048, 2048, 16384, 1024, 1.0f,
                        by * 256, bx * 256, (long long)bz * 2048 * 1024,
                        lds, lds + 32768);
}

extern "C" void kernel_launch(void* const* d_in, const int* in_sizes, int n_in,
                              void* d_out, int out_size, void* d_ws, size_t ws_size,
                              hipStream_t stream) {
  (void)in_sizes; (void)n_in; (void)out_size;
  const float* x  = (const float*)d_in[0];
  const float* Wq = (const float*)d_in[1];
  const float* bq = (const float*)d_in[2];
  const float* Wk = (const float*)d_in[3];
  const float* bk = (const float*)d_in[4];
  const float* Wv = (const float*)d_in[5];
  const float* bv = (const float*)d_in[6];
  float* out = (float*)d_out;

  const int B = 4, S = 2048, D = 1024;
  const long long MX = (long long)B * S;  // 8192

  const long long need = MX * D * 2              // xb
                       + 3LL * D * D * 2         // Wqkv (contiguous after xb)
                       + 2048 * 4                // bQK
                       + MX * 2 * D * 2          // QKb [8192][2048]
                       + 2LL * B * S * S * 2     // E, ET (adjacent)
                       + (long long)D * 16384 * 2 // VTX [1024][16384]
                       + MX * 8 * 4              // psum [8192][8]
                       + MX * 4;                 // il [8192]
  if ((long long)ws_size < need) return;

  char* w = (char*)d_ws;
  u16*   xb   = (u16*)w;   w += MX * D * 2;
  u16*   Wqkv = (u16*)w;   w += 3LL * D * D * 2;  // = xb + MX*D (contiguous)
  float* bQK  = (float*)w; w += 2048 * 4;
  u16*   QKb  = (u16*)w;   w += MX * 2 * D * 2;
  u16*   E    = (u16*)w;   w += (long long)B * S * S * 2;
  u16*   ET   = (u16*)w;   w += (long long)B * S * S * 2;   // = E + 4*S*S
  u16*   VTX  = (u16*)w;   w += (long long)D * 16384 * 2;
  float* psum = (float*)w; w += MX * 8 * 4;
  float* ilv  = (float*)w; w += MX * 4;
  (void)Wqkv; (void)ET;

  dim3 blk256(256), blk512(512);

  // K1: fused converts (xb+Wqkv contiguous) + bias concat (bq|bk -> bQK)
  {
    int xn4 = (int)(MX * D / 4);          // 2097152
    int wn4 = D * D / 4;                  // 262144
    int tot = xn4 + 3 * wn4 + 512;        // + 512 float4 bias units
    k_cvt_all<<<dim3((tot + 255) / 256), blk256, 0, stream>>>(
        x, Wq, Wk, Wv, bq, bk, xb, bQK, xn4, wn4);
  }

  // K2': QK-proj — exactly 1 block/CU round
  k_projQK<<<dim3(256), blk512, 0, stream>>>(xb, Wqkv, bQK, QKb);

  // K3': scores (E, ET, psum) + VT-proj
  k_sc<<<dim3(384), blk512, 0, stream>>>(xb, Wqkv, bv, QKb, E, VTX, psum);

  // K4': il + scaled X^T (VTX cols 8192+) + il array
  k_xt<<<dim3(2048), blk256, 0, stream>>>(xb, psum, ilv, VTX);

  // K5': outputs (out1 row-scaled by il; out2 via ET x X~T)
  k_out<<<dim3(256), blk512, 0, stream>>>(E, VTX, out, ilv);
}